// Round 3
// baseline (64.666 us; speedup 1.0000x reference)
//
#include <hip/hip_runtime.h>
#include <math.h>

// diag-RTRL fused kernel for MI355X (gfx950)
//   s      = tanh(0.9*u + x@W)         [32,1024]
//   u_new  = 0.9*u + x@W               [32,1024]
//   E_new  = 0.9*E + x[:,:,None]       [32,1024,1024]  <-- 268 MB stream, dominates
//
// Round-3 changes vs round-2 (Occupancy 55% showed GEMM was still a ~28 us
// latency-bound tail; E-stream alone is ~35 us, near its HBM floor):
//  * GEMM: LDS-tiled W (16 rows x 256 cols = 16 KB) with register
//    double-buffered prefetch. Converts per-thread scattered 4 KB-stride
//    W loads (latency-bound, ILP 4) into bulk coalesced block loads.
//    GEMM block time ~9 us -> fully hidden under the E-stream.
//  * E-stream: manual 4x unroll (exact 16 trips) -> 4 loads in flight/wave.
//  * Total static LDS 20 KB -> still 8 blocks/CU (no E occupancy loss).

#define BETA 0.9f

constexpr int Bb   = 32;
constexpr int D_IN = 1024;
constexpr int D_H  = 1024;

constexpr int THREADS     = 256;
constexpr int GEMM_BLOCKS = 128;   // 4 blocks per batch row: 256 j-columns each
constexpr int E_BLOCKS    = 2048;  // 8,388,608 float4 / (2048*256) = 16 trips
constexpr int TILE_K      = 16;    // W rows per LDS tile (16 KB tile)

typedef float f4 __attribute__((ext_vector_type(4)));

__global__ __launch_bounds__(THREADS) void diag_rtrl_fused(
    const float* __restrict__ x,   // [32,1024]
    const float* __restrict__ W,   // [1024,1024]
    const float* __restrict__ u,   // [32,1024]
    const float* __restrict__ E,   // [32,1024,1024]
    float* __restrict__ out)       // [s | u_new | E_new]
{
    __shared__ f4    tile4[TILE_K][64];   // 16 rows x 256 cols, 16 KB
    __shared__ float xs[D_IN];            // 4 KB x-row

    const int blk = blockIdx.x;
    const int tid = threadIdx.x;

    if (blk < GEMM_BLOCKS) {
        // ---- GEMM + tanh: b = blk/4, columns j in [(blk%4)*256, +256) ----
        const int b     = blk >> 2;
        const int jbase = (blk & 3) * 256;

        for (int i = tid; i < D_IN; i += THREADS)
            xs[i] = x[b * D_IN + i];

        const float* tilef = (const float*)tile4;
        const f4* __restrict__ W4 = (const f4*)W;  // row stride 256 f4

        // cooperative tile load: thread covers rows r0+{0,4,8,12}, f4-col c4
        const int r0 = tid >> 6;     // 0..3
        const int c4 = tid & 63;     // 0..63
        const int wcol = (jbase >> 2) + c4;

        f4 n0, n1, n2, n3;
        {   // prefetch tile 0
            const f4* p = W4 + r0 * 256 + wcol;
            n0 = p[0]; n1 = p[4 * 256]; n2 = p[8 * 256]; n3 = p[12 * 256];
        }

        float a0 = 0.f, a1 = 0.f, a2 = 0.f, a3 = 0.f;

        for (int t = 0; t < D_IN / TILE_K; ++t) {       // 64 tiles
            __syncthreads();                            // prev reads done (also covers xs at t=0)
            tile4[r0 + 0][c4] = n0;
            tile4[r0 + 4][c4] = n1;
            tile4[r0 + 8][c4] = n2;
            tile4[r0 + 12][c4] = n3;
            __syncthreads();

            if (t < D_IN / TILE_K - 1) {                // prefetch next tile
                const f4* p = W4 + ((t + 1) * TILE_K + r0) * 256 + wcol;
                n0 = p[0]; n1 = p[4 * 256]; n2 = p[8 * 256]; n3 = p[12 * 256];
            }

            const int i0 = t * TILE_K;
            #pragma unroll
            for (int r = 0; r < TILE_K; r += 4) {
                a0 = fmaf(xs[i0 + r + 0], tilef[(r + 0) * 256 + tid], a0);
                a1 = fmaf(xs[i0 + r + 1], tilef[(r + 1) * 256 + tid], a1);
                a2 = fmaf(xs[i0 + r + 2], tilef[(r + 2) * 256 + tid], a2);
                a3 = fmaf(xs[i0 + r + 3], tilef[(r + 3) * 256 + tid], a3);
            }
        }

        const float acc = (a0 + a1) + (a2 + a3);
        const int   t   = b * D_H + jbase + tid;
        const float un  = BETA * u[t] + acc;
        out[t]            = tanhf(un);   // s
        out[Bb * D_H + t] = un;          // u_new
    } else {
        // ---- E stream: E_new = 0.9*E + x[b,i], float4, 4x unrolled ----
        const f4* __restrict__ E4 = (const f4*)E;
        f4* __restrict__ O4 = (f4*)(out + 2 * Bb * D_H);

        const int stride = E_BLOCKS * THREADS;          // 524,288
        int v = (blk - GEMM_BLOCKS) * THREADS + tid;

        #pragma unroll
        for (int it = 0; it < 4; ++it) {                // 16 total trips
            const int v0 = v, v1 = v + stride, v2 = v + 2 * stride, v3 = v + 3 * stride;
            f4 e0 = E4[v0];
            f4 e1 = E4[v1];
            f4 e2 = E4[v2];
            f4 e3 = E4[v3];
            const float x0 = x[v0 >> 8];
            const float x1 = x[v1 >> 8];
            const float x2 = x[v2 >> 8];
            const float x3 = x[v3 >> 8];
            __builtin_nontemporal_store(e0 * BETA + x0, &O4[v0]);
            __builtin_nontemporal_store(e1 * BETA + x1, &O4[v1]);
            __builtin_nontemporal_store(e2 * BETA + x2, &O4[v2]);
            __builtin_nontemporal_store(e3 * BETA + x3, &O4[v3]);
            v += 4 * stride;
        }
    }
}

extern "C" void kernel_launch(void* const* d_in, const int* in_sizes, int n_in,
                              void* d_out, int out_size, void* d_ws, size_t ws_size,
                              hipStream_t stream) {
    const float* x = (const float*)d_in[0];
    const float* W = (const float*)d_in[1];
    const float* u = (const float*)d_in[2];
    const float* E = (const float*)d_in[3];
    float* out = (float*)d_out;

    const int grid = GEMM_BLOCKS + E_BLOCKS;
    diag_rtrl_fused<<<grid, THREADS, 0, stream>>>(x, W, u, E, out);
}

// Round 4
// 48.575 us; speedup vs baseline: 1.3313x; 1.3313x over previous
//
#include <hip/hip_runtime.h>
#include <math.h>

// diag-RTRL, round 4: split-K GEMM distributed across the streaming grid.
//   s      = tanh(0.9*u + x@W)         [32,1024]
//   u_new  = 0.9*u + x@W               [32,1024]
//   E_new  = 0.9*E + x[:,:,None]       [32,1024,1024]  (268 MB stream, dominates)
//
// Round-3 lesson: ANY "few big blocks own the GEMM" design leaves a
// latency-bound tail (Occupancy 41%, dur 64.7us). Fix: split-K.
//  * k1 (2048 blocks): 512 blocks each compute ONE small tile
//    (64 j-cols x 32 k-rows, 12 KB LDS) of partial dot products ->
//    d_ws[k][b][j] (4 MB, each slot written exactly once: no atomics,
//    no zero-init, deterministic). EVERY block also streams a contiguous
//    E region; GEMM blocks take 13 trips, plain blocks 17, so the extra
//    tile work is balanced (512*13 + 1536*17 = 32768 = all trips).
//  * k2 (128 blocks): acc = sum_k ws[k][b][j]; u_new, tanh, store. ~3us,
//    reads 4 MB from L2.

#define BETA 0.9f

constexpr int Bb   = 32;
constexpr int D_IN = 1024;
constexpr int D_H  = 1024;

constexpr int THREADS    = 256;
constexpr int KSPLIT     = 32;                 // 32 k-chunks of 32 rows
constexpr int JTILES     = 16;                 // 16 j-tiles of 64 cols
constexpr int GEMM_TILES = KSPLIT * JTILES;    // 512 blocks carry a tile
constexpr int GRID1      = 2048;
constexpr int TRIPS_G    = 13;                 // E trips for tile-carrying blocks
constexpr int TRIPS_E    = 17;                 // E trips for plain blocks
// 512*13 + 1536*17 = 32768 trips * 256 f4 = 8,388,608 f4 = full E. 

typedef float f4 __attribute__((ext_vector_type(4)));

__global__ __launch_bounds__(THREADS) void rtrl_k1(
    const float* __restrict__ x,   // [32,1024]
    const float* __restrict__ W,   // [1024,1024]
    const float* __restrict__ E,   // [32,1024,1024]
    float* __restrict__ out,       // [s | u_new | E_new]
    float* __restrict__ ws)        // [KSPLIT][32][1024] partials
{
    __shared__ float Wt[32][64];   // 8 KB  : k-chunk x j-tile of W
    __shared__ float xs[32][32];   // 4 KB  : all b x k-chunk of x

    const int blk = blockIdx.x;
    const int tid = threadIdx.x;

    if (blk < GEMM_TILES) {
        // ---------- one GEMM tile: kt = k-chunk, jt = j-tile ----------
        const int kt = blk >> 4;          // 0..31
        const int jt = blk & 15;          // 0..15
        const int i0 = kt * 32;
        const int j0 = jt * 64;

        const f4* __restrict__ W4 = (const f4*)W;   // row stride 256 f4
        const f4* __restrict__ x4 = (const f4*)x;   // row stride 256 f4

        // load W tile: 32 rows x 16 f4 = 512 f4, 2 per thread
        {
            f4* Wt4 = (f4*)Wt;
            #pragma unroll
            for (int p = 0; p < 2; ++p) {
                const int idx = tid + p * 256;
                const int row = idx >> 4, c4 = idx & 15;
                Wt4[row * 16 + c4] = W4[(i0 + row) * 256 + (j0 >> 2) + c4];
            }
        }
        // load x tile: 32 b x 8 f4 = 256 f4, 1 per thread
        {
            f4* xs4 = (f4*)xs;
            const int row = tid >> 3, c4 = tid & 7;
            xs4[row * 8 + c4] = x4[row * 256 + (i0 >> 2) + c4];
        }
        __syncthreads();

        // compute: each thread -> 8 batch rows, one j column
        const int bg = tid >> 6;          // wave-uniform: 8-batch group
        const int jc = tid & 63;          // column within tile
        float a0=0,a1=0,a2=0,a3=0,a4=0,a5=0,a6=0,a7=0;
        #pragma unroll 8
        for (int i = 0; i < 32; ++i) {
            const float wv = Wt[i][jc];   // 64 consecutive lanes: conflict-free
            a0 = fmaf(xs[bg*8+0][i], wv, a0);  // xs reads broadcast (uniform addr)
            a1 = fmaf(xs[bg*8+1][i], wv, a1);
            a2 = fmaf(xs[bg*8+2][i], wv, a2);
            a3 = fmaf(xs[bg*8+3][i], wv, a3);
            a4 = fmaf(xs[bg*8+4][i], wv, a4);
            a5 = fmaf(xs[bg*8+5][i], wv, a5);
            a6 = fmaf(xs[bg*8+6][i], wv, a6);
            a7 = fmaf(xs[bg*8+7][i], wv, a7);
        }
        float acc[8] = {a0,a1,a2,a3,a4,a5,a6,a7};
        #pragma unroll
        for (int bb = 0; bb < 8; ++bb) {
            const int b = bg * 8 + bb;
            ws[(kt * Bb + b) * D_H + j0 + jc] = acc[bb];   // coalesced
        }
    }

    // ---------- E stream: contiguous region per block ----------
    const f4* __restrict__ E4 = (const f4*)E;
    f4* __restrict__ O4 = (f4*)(out + 2 * Bb * D_H);

    const int ntrips = (blk < GEMM_TILES) ? TRIPS_G : TRIPS_E;
    const int r0     = (blk < GEMM_TILES)
                     ? blk * (TRIPS_G * THREADS)
                     : GEMM_TILES * (TRIPS_G * THREADS) + (blk - GEMM_TILES) * (TRIPS_E * THREADS);

    int v = r0 + tid;
    int t = 0;
    for (; t + 4 <= ntrips; t += 4) {     // 4 loads in flight
        f4 e0 = E4[v];
        f4 e1 = E4[v + 256];
        f4 e2 = E4[v + 512];
        f4 e3 = E4[v + 768];
        const float x0 = x[v >> 8];
        const float x1 = x[(v + 256) >> 8];
        const float x2 = x[(v + 512) >> 8];
        const float x3 = x[(v + 768) >> 8];
        __builtin_nontemporal_store(e0 * BETA + x0, &O4[v]);
        __builtin_nontemporal_store(e1 * BETA + x1, &O4[v + 256]);
        __builtin_nontemporal_store(e2 * BETA + x2, &O4[v + 512]);
        __builtin_nontemporal_store(e3 * BETA + x3, &O4[v + 768]);
        v += 1024;
    }
    for (; t < ntrips; ++t) {
        f4 e = E4[v];
        const float xv = x[v >> 8];
        __builtin_nontemporal_store(e * BETA + xv, &O4[v]);
        v += 256;
    }
}

__global__ __launch_bounds__(THREADS) void rtrl_k2(
    const float* __restrict__ ws,  // [KSPLIT][32][1024]
    const float* __restrict__ u,   // [32,1024]
    float* __restrict__ out)       // [s | u_new | ...]
{
    const int t = blockIdx.x * THREADS + threadIdx.x;   // output (b,j), 32768 total
    float acc = 0.f;
    #pragma unroll
    for (int k = 0; k < KSPLIT; ++k)
        acc += ws[k * (Bb * D_H) + t];                  // coalesced, L2-resident
    const float un = BETA * u[t] + acc;
    out[t]            = tanhf(un);   // s
    out[Bb * D_H + t] = un;          // u_new
}

extern "C" void kernel_launch(void* const* d_in, const int* in_sizes, int n_in,
                              void* d_out, int out_size, void* d_ws, size_t ws_size,
                              hipStream_t stream) {
    const float* x = (const float*)d_in[0];
    const float* W = (const float*)d_in[1];
    const float* u = (const float*)d_in[2];
    const float* E = (const float*)d_in[3];
    float* out = (float*)d_out;
    float* ws  = (float*)d_ws;     // needs KSPLIT*32*1024*4 = 4 MB

    rtrl_k1<<<GRID1, THREADS, 0, stream>>>(x, W, E, out, ws);
    rtrl_k2<<<(Bb * D_H) / THREADS, THREADS, 0, stream>>>(ws, u, out);
}